// Round 12
// baseline (125.485 us; speedup 1.0000x reference)
//
#include <hip/hip_runtime.h>

typedef __attribute__((ext_vector_type(8))) short short8v;
typedef __attribute__((ext_vector_type(4))) float f32x4;
typedef __attribute__((ext_vector_type(2))) float f32x2;
typedef __attribute__((ext_vector_type(4))) unsigned int u32x4;

constexpr int Bsz = 4;
constexpr int Hh = 64, Wwd = 64;
constexpr int HWp = Hh * Wwd;            // 4096
constexpr int NPIX = Bsz * HWp;          // 16384
constexpr int HH = 66;                   // halo dim
constexpr int HPIX = HH * HH;            // 4356
constexpr int Kdim = 2304;               // 9*256
constexpr int NSTEP = 36;                // Kdim / 64

// ---- workspace byte offsets
constexpr size_t B_H1H  = 0;
constexpr size_t HALO_BYTES = (size_t)Bsz * HPIX * 256 * 2;      // 8,921,088
constexpr size_t B_H2H  = B_H1H + HALO_BYTES;
constexpr size_t B_XTH  = B_H2H + HALO_BYTES;
constexpr size_t B_PROD = B_XTH + HALO_BYTES;
constexpr size_t B_OFFP = B_PROD + (size_t)NPIX * 4;
constexpr size_t B_WB2  = B_OFFP + (size_t)NPIX * 32 * 4;        // frag-packed (64-o tiles)
constexpr size_t B_WBD  = B_WB2 + (size_t)256 * Kdim * 2;        // frag-packed (64-o tiles)
constexpr size_t B_WB3  = B_WBD + (size_t)256 * Kdim * 2;        // linear (conv3g)

static __device__ __forceinline__ unsigned short f2bf(float f) {
    unsigned u = __builtin_bit_cast(unsigned, f);
    u += 0x7FFFu + ((u >> 16) & 1u);
    return (unsigned short)(u >> 16);
}
static __device__ __forceinline__ unsigned cvt_pk_bf16(float lo, float hi) {
    unsigned r;
    asm("v_cvt_pk_bf16_f32 %0, %1, %2" : "=v"(r) : "v"(lo), "v"(hi));
    return r;
}
static __device__ __forceinline__ f32x2 pk_mul(f32x2 a, f32x2 b) {
    f32x2 d;
    asm("v_pk_mul_f32 %0, %1, %2" : "=v"(d) : "v"(a), "v"(b));
    return d;
}
static __device__ __forceinline__ f32x2 pk_fma(f32x2 a, f32x2 b, f32x2 c) {
    f32x2 d;
    asm("v_pk_fma_f32 %0, %1, %2, %3" : "=v"(d) : "v"(a), "v"(b), "v"(c));
    return d;
}
static __device__ __forceinline__ f32x2 unpack2(unsigned u) {
    f32x2 v;
    v.x = __builtin_bit_cast(float, u << 16);
    v.y = __builtin_bit_cast(float, u & 0xFFFF0000u);
    return v;
}
static __device__ __forceinline__ void gload_lds16(const void* g, void* l) {
    __builtin_amdgcn_global_load_lds((const __attribute__((address_space(1))) unsigned int*)g,
                                     (__attribute__((address_space(3))) unsigned int*)l, 16, 0, 0);
}
static __device__ __forceinline__ int swz(int u) {
    return (((u & 7) ^ ((u >> 3) & 7)) << 3);
}

// ---------------------------------------------------------------- zero halo rings + prod
__global__ void k_zero_ring(unsigned short* h1h, unsigned short* h2h, unsigned short* xth,
                            float* prod) {
    int blk = blockIdx.x;
    if (blk >= 3120) {
        unsigned* p = (unsigned*)prod + (size_t)(blk - 3120) * 128 + threadIdx.x;
        *p = 0;
        return;
    }
    int img = blk / 260;
    int rp = blk - img * 260;
    int buf = img >> 2, b = img & 3;
    int y, x;
    if (rp < 66) { y = 0; x = rp; }
    else if (rp < 132) { y = 65; x = rp - 66; }
    else { int s2 = rp - 132; y = 1 + (s2 >> 1); x = (s2 & 1) * 65; }
    unsigned short* base = (buf == 0) ? h1h : (buf == 1) ? h2h : xth;
    unsigned* p = (unsigned*)(base + ((size_t)b * HPIX + y * HH + x) * 256);
    p[threadIdx.x] = 0;
}

// ---------------------------------------------------------------- fused: x_ref->xth transpose + prod partial
__global__ void k_prodx(const float* __restrict__ xr, const float* __restrict__ xn,
                        unsigned short* __restrict__ xth, float* __restrict__ prod) {
    __shared__ float t[32][33];
    __shared__ float red[8][33];
    int b = blockIdx.z;
    int c0 = blockIdx.y * 32;
    int y = blockIdx.x >> 1, x0 = (blockIdx.x & 1) * 32;
    int tx = threadIdx.x, ty = threadIdx.y;
    float part = 0.f;
#pragma unroll
    for (int i = 0; i < 32; i += 8) {
        size_t idx = ((size_t)b * 256 + c0 + ty + i) * HWp + y * Wwd + x0 + tx;
        float vr = xr[idx];
        float vn = xn[idx];
        t[ty + i][tx] = vr;
        part = fmaf(vr, vn, part);
    }
    red[ty][tx] = part;
    __syncthreads();
#pragma unroll
    for (int i = 0; i < 32; i += 8)
        xth[((size_t)b * HPIX + (y + 1) * HH + (x0 + ty + i + 1)) * 256 + c0 + tx] =
            f2bf(t[tx][ty + i]);
    if (ty == 0) {
        float s = red[0][tx] + red[1][tx] + red[2][tx] + red[3][tx] +
                  red[4][tx] + red[5][tx] + red[6][tx] + red[7][tx];
        atomicAdd(&prod[b * HWp + y * Wwd + x0 + tx], s);
    }
}

// ---------------------------------------------------------------- fused: corr (box3x3+leaky) + conv1 -> h1h
__global__ __launch_bounds__(256) void k_conv1c(const float* __restrict__ prod,
                                                const float* __restrict__ w1,
                                                const float* __restrict__ b1,
                                                unsigned short* __restrict__ h1h) {
    __shared__ float pp[5][36];
    __shared__ float pt[3][34];
    int px0 = blockIdx.x * 32;
    int b = px0 >> 12, y = (px0 & 4095) >> 6, x0 = px0 & 63;
    int tid = threadIdx.x;
    if (tid < 180) {
        int i = tid / 36, j = tid - i * 36;
        int yy = y - 2 + i, xx = x0 - 2 + j;
        float v = 0.f;
        if (yy >= 0 && yy < Hh && xx >= 0 && xx < Wwd) v = prod[b * HWp + yy * Wwd + xx];
        pp[i][j] = v;
    }
    __syncthreads();
    if (tid < 102) {
        int i = tid / 34, j = tid - i * 34;
        int yy = y - 1 + i, xx = x0 - 1 + j;
        float v = 0.f;
        if (yy >= 0 && yy < Hh && xx >= 0 && xx < Wwd) {
            float s = pp[i][j]     + pp[i][j + 1]     + pp[i][j + 2] +
                      pp[i + 1][j] + pp[i + 1][j + 1] + pp[i + 1][j + 2] +
                      pp[i + 2][j] + pp[i + 2][j + 1] + pp[i + 2][j + 2];
            s *= (1.0f / 256.0f);
            v = (s > 0.f) ? s : 0.1f * s;
        }
        pt[i][j] = v;
    }
    float wl[9];
#pragma unroll
    for (int k = 0; k < 9; ++k) wl[k] = w1[tid * 9 + k];
    float bias = b1[tid];
    __syncthreads();
    for (int p = 0; p < 32; ++p) {
        float acc = bias;
#pragma unroll
        for (int ky = 0; ky < 3; ++ky)
#pragma unroll
            for (int kx = 0; kx < 3; ++kx) acc = fmaf(pt[ky][p + kx], wl[ky * 3 + kx], acc);
        acc = fmaxf(acc, 0.f);
        h1h[((size_t)b * HPIX + (y + 1) * HH + (x0 + p + 1)) * 256 + tid] = f2bf(acc);
    }
}

// ---------------------------------------------------------------- all weight packs (R6-style 64-o tiles)
// frag idx = ((((ot*36+s)*2+kf)*4+mi)*64+lane)*8+e ; o=ot*64+mi*16+(lane&15); kk=s*64+(kf*4+(lane>>4))*8+e
__global__ void k_packall(const float* __restrict__ w2, const float* __restrict__ wd,
                          const float* __restrict__ w3,
                          unsigned short* __restrict__ wb2f, unsigned short* __restrict__ wbdf,
                          unsigned short* __restrict__ wb3) {
    int blk = blockIdx.x;
    if (blk < 4608) {
        const float* w = (blk < 2304) ? w2 : wd;
        unsigned short* out = (blk < 2304) ? wb2f : wbdf;
        int i = (blk % 2304) * 256 + threadIdx.x;
        int e = i & 7;
        int lane = (i >> 3) & 63;
        int mi = (i >> 9) & 3;
        int kf = (i >> 11) & 1;
        int rest = i >> 12;                           // [0,144)
        int s = rest % 36;
        int ot = rest / 36;                           // [0,4)
        int o = ot * 64 + mi * 16 + (lane & 15);
        int kk = s * 64 + (kf * 4 + (lane >> 4)) * 8 + e;
        int c = kk & 255, tap = kk >> 8;
        out[i] = f2bf(w[((size_t)o * 256 + c) * 9 + tap]);
    } else {
        int i = (blk - 4608) * 256 + threadIdx.x;
        int o = i / Kdim;
        int r = i - o * Kdim;
        int k = r >> 8, c = r & 255;
        float v = (o < 18) ? w3[((size_t)o * 256 + c) * 9 + k] : 0.f;
        wb3[i] = f2bf(v);
    }
}

// ---------------------------------------------------------------- conv2 GEMM: 64px x 128o, 4 waves px-split, 2 blocks/CU
__global__ __launch_bounds__(256) void k_conv2g(const unsigned short* __restrict__ h1h,
                                                const unsigned short* __restrict__ wbf,
                                                const float* __restrict__ bias,
                                                unsigned short* __restrict__ h2h) {
    __shared__ short S_s[2][64 * 64];
    const int tid = threadIdx.x;
    const int bid = blockIdx.x;
    const int lin = (bid & 7) * 64 + (bid >> 3);      // XCD-bijective, 512 blocks
    const int px0 = (lin >> 1) * 64;
    const int oblk = lin & 1;
    const int b = px0 >> 12;
    const unsigned short* hb = h1h + (size_t)b * HPIX * 256;
    const int pxl = tid >> 2;
    const int px = px0 + pxl;
    const int y = (px & 4095) >> 6, x = px & 63;
    const int u0 = (tid & 3) * 2;
    const int lane = tid & 63, wv = tid >> 6;
    const int pg = wv & 1;                             // px-group (32 px)
    const int og = oblk * 2 + (wv >> 1);               // global 64-o tile
    const unsigned short* wfb = wbf + (size_t)og * NSTEP * 4096 + lane * 8;
    const unsigned short* abase0 = hb + (size_t)((y + 1) * HH + (x + 1)) * 256 + u0 * 8;

    f32x4 acc[2][4] = {};                              // [pi(px 2x16)][oi(o 4x16)]
    u32x4 wA[8], wB[8], aA0, aA1, aB0, aB1;
    float bia[4];
#pragma unroll
    for (int oi = 0; oi < 4; ++oi) bia[oi] = bias[og * 64 + oi * 16 + (lane & 15)];

    const int wr0 = pxl * 64 + ((u0 ^ (pxl & 7)) << 3);
    const int wr1 = pxl * 64 + (((u0 + 1) ^ (pxl & 7)) << 3);

    auto WLOAD = [&](int s, u32x4 (&wreg)[8]) {
#pragma unroll
        for (int f = 0; f < 8; ++f)
            wreg[f] = *(const u32x4*)(wfb + ((size_t)s * 8 + f) * 512);
    };
    auto ALOAD = [&](int s, u32x4& a0, u32x4& a1) {
        int tap = s >> 2, chunk = s & 3;
        int aoff = ((tap / 3 - 1) * HH + (tap % 3 - 1)) * 256 + chunk * 64;
        a0 = *(const u32x4*)(abase0 + aoff);
        a1 = *(const u32x4*)(abase0 + aoff + 8);
    };

    {
        u32x4 a0, a1;
        ALOAD(0, a0, a1);
        WLOAD(0, wA);
        *(u32x4*)&S_s[0][wr0] = a0;
        *(u32x4*)&S_s[0][wr1] = a1;
        ALOAD(1, aA0, aA1);
        asm volatile("s_waitcnt lgkmcnt(0)" ::: "memory");
    }

    auto ITER = [&](int s, u32x4 (&wcur)[8], u32x4 (&wnxt)[8],
                    u32x4& aC0, u32x4& aC1, u32x4& aN0, u32x4& aN1,
                    short* SBc, short* SBn) {
        __builtin_amdgcn_s_barrier();
        __builtin_amdgcn_sched_barrier(0);
        if (s + 1 < NSTEP) {
            *(u32x4*)&SBn[wr0] = aC0;
            *(u32x4*)&SBn[wr1] = aC1;
        }
        if (s + 2 < NSTEP) ALOAD(s + 2, aN0, aN1);
        if (s + 1 < NSTEP) WLOAD(s + 1, wnxt);
        short8v af[2][2];
#pragma unroll
        for (int pi = 0; pi < 2; ++pi) {
            int row = pg * 32 + pi * 16 + (lane & 15);
#pragma unroll
            for (int kf = 0; kf < 2; ++kf) {
                int c8 = kf * 4 + (lane >> 4);
                af[pi][kf] = *(const short8v*)&SBc[row * 64 + ((c8 ^ (row & 7)) << 3)];
            }
        }
        __builtin_amdgcn_s_setprio(1);
#pragma unroll
        for (int kf = 0; kf < 2; ++kf)
#pragma unroll
            for (int pi = 0; pi < 2; ++pi)
#pragma unroll
                for (int oi = 0; oi < 4; ++oi)
                    acc[pi][oi] = __builtin_amdgcn_mfma_f32_16x16x32_bf16(
                        af[pi][kf], __builtin_bit_cast(short8v, wcur[kf * 4 + oi]),
                        acc[pi][oi], 0, 0, 0);
        __builtin_amdgcn_s_setprio(0);
        asm volatile("s_waitcnt lgkmcnt(0)" ::: "memory");
    };

    for (int s2 = 0; s2 < NSTEP; s2 += 2) {
        ITER(s2, wA, wB, aA0, aA1, aB0, aB1, &S_s[0][0], &S_s[1][0]);
        ITER(s2 + 1, wB, wA, aB0, aB1, aA0, aA1, &S_s[1][0], &S_s[0][0]);
    }

#pragma unroll
    for (int pi = 0; pi < 2; ++pi) {
#pragma unroll
        for (int j = 0; j < 4; ++j) {
            int p2 = px0 + pg * 32 + pi * 16 + (lane >> 4) * 4 + j;
            int yy = (p2 & 4095) >> 6, xx = p2 & 63;
            unsigned short* dst = h2h + ((size_t)b * HPIX + (yy + 1) * HH + (xx + 1)) * 256;
#pragma unroll
            for (int oi = 0; oi < 4; ++oi) {
                int o = og * 64 + oi * 16 + (lane & 15);
                dst[o] = f2bf(fmaxf(acc[pi][oi][j] + bia[oi], 0.f));
            }
        }
    }
}

// ---------------------------------------------------------------- conv3 GEMM: 64px x 32o, BK=64, dbuf
__global__ __launch_bounds__(256) void k_conv3g(const unsigned short* __restrict__ h2h,
                                                const unsigned short* __restrict__ wb,
                                                const float* __restrict__ bias,
                                                float* __restrict__ offp) {
    __shared__ short A_s[2][64 * 64];
    __shared__ short B_s[2][32 * 64];
    const int tid = threadIdx.x;
    const int px0 = blockIdx.x * 64;
    const int b = px0 >> 12;
    const unsigned short* hb = h2h + (size_t)b * HPIX * 256;

    const unsigned short* abase[2];
#pragma unroll
    for (int i = 0; i < 2; ++i) {
        int u = i * 256 + tid;
        int pxl = u >> 3;
        int pxg = px0 + pxl;
        int y = (pxg & 4095) >> 6, x = pxg & 63;
        abase[i] = hb + (size_t)((y + 1) * HH + (x + 1)) * 256 + swz(u);
    }
    const unsigned short* bbase = wb + (size_t)(tid >> 3) * Kdim + swz(tid);

    const int lane = tid & 63, wv = tid >> 6;
    f32x4 acc[2] = {};

    auto STAGE = [&](int s, int buf) {
        int tap = s >> 2, chunk = s & 3;
        int delta = ((tap / 3 - 1) * HH + (tap % 3 - 1)) * 256 + chunk * 64;
        short* Ab = &A_s[buf][0];
#pragma unroll
        for (int i = 0; i < 2; ++i) gload_lds16(abase[i] + delta, Ab + (i * 256 + tid) * 8);
        gload_lds16(bbase + s * 64, &B_s[buf][tid * 8]);
    };

    STAGE(0, 0);
    __syncthreads();
    for (int s = 0; s < NSTEP; ++s) {
        int cur = s & 1;
        if (s + 1 < NSTEP) STAGE(s + 1, cur ^ 1);
        const short* Ab = &A_s[cur][0];
        const short* Bb = &B_s[cur][0];
        short8v af[2], bf[2][2];
#pragma unroll
        for (int kf = 0; kf < 2; ++kf) {
            int row = wv * 16 + (lane & 15);
            int c8 = kf * 4 + (lane >> 4);
            af[kf] = *(const short8v*)&Ab[row * 64 + ((c8 ^ (row & 7)) << 3)];
        }
#pragma unroll
        for (int ni = 0; ni < 2; ++ni) {
            int row = ni * 16 + (lane & 15);
#pragma unroll
            for (int kf = 0; kf < 2; ++kf) {
                int c8 = kf * 4 + (lane >> 4);
                bf[ni][kf] = *(const short8v*)&Bb[row * 64 + ((c8 ^ (row & 7)) << 3)];
            }
        }
#pragma unroll
        for (int kf = 0; kf < 2; ++kf)
#pragma unroll
            for (int ni = 0; ni < 2; ++ni)
                acc[ni] = __builtin_amdgcn_mfma_f32_16x16x32_bf16(af[kf], bf[ni][kf], acc[ni], 0, 0, 0);
        __syncthreads();
    }
#pragma unroll
    for (int j = 0; j < 4; ++j) {
        int px = px0 + wv * 16 + (lane >> 4) * 4 + j;
#pragma unroll
        for (int ni = 0; ni < 2; ++ni) {
            int o = ni * 16 + (lane & 15);
            float bv = (o < 18) ? bias[o] : 0.f;
            offp[(size_t)px * 32 + o] = fmaxf(acc[ni][j] + bv, 0.f);
        }
    }
}

// ---------------------------------------------------------------- dcn GEMM: 64px x 256o, 8 waves px-split (2pg x 4ot), ITER2
__global__ __launch_bounds__(512) void k_dcng(const unsigned short* __restrict__ xth,
                                              const float* __restrict__ offp,
                                              const unsigned short* __restrict__ wbf,
                                              const float* __restrict__ xn,
                                              float* __restrict__ out) {
    __shared__ short S_s[4][64 * 64];                 // 4 bufs, 32 KB
    const int tid = threadIdx.x;
    const int bid = blockIdx.x;
    const int px0 = ((bid & 7) * 32 + (bid >> 3)) * 64;   // XCD-bijective
    const int b = px0 >> 12;
    const unsigned short* xb = xth + (size_t)b * HPIX * 256;
    const int pxl = tid >> 3;
    const int px = px0 + pxl;
    const int y = (px & 4095) >> 6, x = px & 63;
    const int u0 = tid & 7;
    const int lane = tid & 63, wv = tid >> 6;
    const int pg = wv & 1;                             // px-group (32 px)
    const int ot = wv >> 1;                            // 64-o tile
    const unsigned short* wfb = wbf + (size_t)ot * NSTEP * 4096 + lane * 8;
    const float2* offv = (const float2*)offp;

    f32x4 acc[4][2] = {};                              // [mi(o 4x16)][ni(px 2x16)]
    u32x4 wA[2][8], wB[2][8];                          // [half][kf*4+mi]
    u32x4 g[2][4];
    const int wr0 = pxl * 64 + ((u0 ^ (pxl & 7)) << 3);

    const unsigned short* pcorner[4];
    f32x2 wpair[4];
    float2 offn;

    auto SETUP = [&](int tap, float dyo, float dxo) {
        int ky = tap / 3 - 1, kx = tap % 3 - 1;
        float ypos = (float)(y + ky) + dyo;
        float xpos = (float)(x + kx) + dxo;
        float y0f = floorf(ypos), x0f = floorf(xpos);
        float wy = ypos - y0f, wx = xpos - x0f;
        int y0 = (int)y0f, x0 = (int)x0f;
        bool y0v = (y0 >= 0) && (y0 < Hh), y1v = (y0 + 1 >= 0) && (y0 + 1 < Hh);
        bool x0v = (x0 >= 0) && (x0 < Wwd), x1v = (x0 + 1 >= 0) && (x0 + 1 < Wwd);
        int hy0 = min(max(y0, -1), 64) + 1, hy1 = min(max(y0 + 1, -1), 64) + 1;
        int hx0 = min(max(x0, -1), 64) + 1, hx1 = min(max(x0 + 1, -1), 64) + 1;
        float w0 = (1.f - wy) * (1.f - wx) * (float)(y0v && x0v);
        float w1 = (1.f - wy) * wx * (float)(y0v && x1v);
        float w2 = wy * (1.f - wx) * (float)(y1v && x0v);
        float w3 = wy * wx * (float)(y1v && x1v);
        wpair[0] = (f32x2){w0, w0};
        wpair[1] = (f32x2){w1, w1};
        wpair[2] = (f32x2){w2, w2};
        wpair[3] = (f32x2){w3, w3};
        pcorner[0] = xb + (size_t)((hy0 * HH + hx0) * 256) + u0 * 8;
        pcorner[1] = xb + (size_t)((hy0 * HH + hx1) * 256) + u0 * 8;
        pcorner[2] = xb + (size_t)((hy1 * HH + hx0) * 256) + u0 * 8;
        pcorner[3] = xb + (size_t)((hy1 * HH + hx1) * 256) + u0 * 8;
    };
    auto WLOAD = [&](int s, u32x4 (&wreg)[8]) {
#pragma unroll
        for (int f = 0; f < 8; ++f)
            wreg[f] = *(const u32x4*)(wfb + ((size_t)s * 8 + f) * 512);
    };
    auto GISSUE = [&](int s, u32x4 (&gr)[4]) {
        const int nco = (s & 3) * 64;
#pragma unroll
        for (int c = 0; c < 4; ++c) gr[c] = *(const u32x4*)(pcorner[c] + nco);
    };
    auto COMBINE_WRITE = [&](u32x4 (&gr)[4], short* SBn) {
        u32x4 res;
#pragma unroll
        for (int qd = 0; qd < 4; ++qd) {
            f32x2 a = pk_mul(unpack2(gr[0][qd]), wpair[0]);
            a = pk_fma(unpack2(gr[1][qd]), wpair[1], a);
            a = pk_fma(unpack2(gr[2][qd]), wpair[2], a);
            a = pk_fma(unpack2(gr[3][qd]), wpair[3], a);
            res[qd] = cvt_pk_bf16(a.x, a.y);
        }
        *(u32x4*)&SBn[wr0] = res;
    };

    // prologue
    {
        float2 o0 = offv[(size_t)px * 16];
        SETUP(0, o0.x, o0.y);
        u32x4 g0[4], g1[4];
        GISSUE(0, g0);
        GISSUE(1, g1);
        WLOAD(0, wA[0]);
        WLOAD(1, wA[1]);
        COMBINE_WRITE(g0, &S_s[0][0]);
        COMBINE_WRITE(g1, &S_s[1][0]);
        GISSUE(2, g[0]);
        GISSUE(3, g[1]);
        offn = offv[(size_t)px * 16 + 1];
        asm volatile("s_waitcnt lgkmcnt(0)" ::: "memory");
    }

    auto ITER2 = [&](int s, u32x4 (&wcur)[2][8], u32x4 (&wnxt)[2][8], short* SBc, short* SBn) {
        __builtin_amdgcn_s_barrier();
        __builtin_amdgcn_sched_barrier(0);
        if (s + 2 < NSTEP) {
            COMBINE_WRITE(g[0], SBn);
            COMBINE_WRITE(g[1], SBn + 64 * 64);
        }
        if ((s & 3) == 0 && s + 4 < NSTEP)
            SETUP((s + 4) >> 2, offn.x, offn.y);
        if ((s & 3) == 2 && ((s + 8) >> 2) < 9)
            offn = offv[(size_t)px * 16 + ((s + 8) >> 2)];
        if (s + 4 < NSTEP) {
            GISSUE(s + 4, g[0]);
            GISSUE(s + 5, g[1]);
        }
        if (s + 2 < NSTEP) {
            WLOAD(s + 2, wnxt[0]);
            WLOAD(s + 3, wnxt[1]);
        }
#pragma unroll
        for (int half = 0; half < 2; ++half) {
            const short* SB = SBc + half * 64 * 64;
            short8v sf[2][2];
#pragma unroll
            for (int ni = 0; ni < 2; ++ni) {
                int row = pg * 32 + ni * 16 + (lane & 15);
#pragma unroll
                for (int kf = 0; kf < 2; ++kf) {
                    int c8 = kf * 4 + (lane >> 4);
                    sf[ni][kf] = *(const short8v*)&SB[row * 64 + ((c8 ^ (row & 7)) << 3)];
                }
            }
            __builtin_amdgcn_s_setprio(1);
#pragma unroll
            for (int kf = 0; kf < 2; ++kf)
#pragma unroll
                for (int mi = 0; mi < 4; ++mi)
#pragma unroll
                    for (int ni = 0; ni < 2; ++ni)
                        acc[mi][ni] = __builtin_amdgcn_mfma_f32_16x16x32_bf16(
                            __builtin_bit_cast(short8v, wcur[half][kf * 4 + mi]), sf[ni][kf],
                            acc[mi][ni], 0, 0, 0);
            __builtin_amdgcn_s_setprio(0);
        }
        asm volatile("s_waitcnt lgkmcnt(0)" ::: "memory");
    };

    for (int s4 = 0; s4 < NSTEP; s4 += 4) {
        ITER2(s4, wA, wB, &S_s[0][0], &S_s[2][0]);
        ITER2(s4 + 2, wB, wA, &S_s[2][0], &S_s[0][0]);
    }

#pragma unroll
    for (int mi = 0; mi < 4; ++mi) {
        int o = ot * 64 + mi * 16 + (lane >> 4) * 4;
#pragma unroll
        for (int j = 0; j < 4; ++j) {
            size_t rowbase = ((size_t)b * 256 + o + j) * HWp;
#pragma unroll
            for (int ni = 0; ni < 2; ++ni) {
                int p2 = (px0 + pg * 32 + ni * 16 + (lane & 15)) & 4095;
                size_t idx = rowbase + p2;
                out[idx] = 0.5f * (xn[idx] + fmaxf(acc[mi][ni][j], 0.f));
            }
        }
    }
}

extern "C" void kernel_launch(void* const* d_in, const int* in_sizes, int n_in,
                              void* d_out, int out_size, void* d_ws, size_t ws_size,
                              hipStream_t stream) {
    const float* x_ref  = (const float*)d_in[0];
    const float* x_next = (const float*)d_in[1];
    const float* w1 = (const float*)d_in[2];
    const float* b1 = (const float*)d_in[3];
    const float* w2 = (const float*)d_in[4];
    const float* b2 = (const float*)d_in[5];
    const float* w3 = (const float*)d_in[6];
    const float* b3 = (const float*)d_in[7];
    const float* wd = (const float*)d_in[8];
    float* out = (float*)d_out;
    char* ws = (char*)d_ws;

    unsigned short* h1h = (unsigned short*)(ws + B_H1H);
    unsigned short* h2h = (unsigned short*)(ws + B_H2H);
    unsigned short* xth = (unsigned short*)(ws + B_XTH);
    float* prod = (float*)(ws + B_PROD);
    float* offp = (float*)(ws + B_OFFP);
    unsigned short* wb2f = (unsigned short*)(ws + B_WB2);
    unsigned short* wbdf = (unsigned short*)(ws + B_WBD);
    unsigned short* wb3  = (unsigned short*)(ws + B_WB3);

    k_zero_ring<<<3120 + 128, 128, 0, stream>>>(h1h, h2h, xth, prod);
    k_prodx<<<dim3(128, 8, Bsz), dim3(32, 8), 0, stream>>>(x_ref, x_next, xth, prod);
    k_packall<<<4896, 256, 0, stream>>>(w2, wd, w3, wb2f, wbdf, wb3);
    k_conv1c<<<NPIX / 32, 256, 0, stream>>>(prod, w1, b1, h1h);
    k_conv2g<<<512, 256, 0, stream>>>(h1h, wb2f, b2, h2h);
    k_conv3g<<<256, 256, 0, stream>>>(h2h, wb3, b3, offp);
    k_dcng<<<256, 512, 0, stream>>>(xth, offp, wbdf, x_next, out);
}

// Round 13
// 107.467 us; speedup vs baseline: 1.1677x; 1.1677x over previous
//
#include <hip/hip_runtime.h>

typedef __attribute__((ext_vector_type(8))) short short8v;
typedef __attribute__((ext_vector_type(4))) float f32x4;
typedef __attribute__((ext_vector_type(2))) float f32x2;
typedef __attribute__((ext_vector_type(4))) unsigned int u32x4;

constexpr int Bsz = 4;
constexpr int Hh = 64, Wwd = 64;
constexpr int HWp = Hh * Wwd;            // 4096
constexpr int NPIX = Bsz * HWp;          // 16384
constexpr int HH = 66;                   // halo dim
constexpr int HPIX = HH * HH;            // 4356
constexpr int Kdim = 2304;               // 9*256
constexpr int NSTEP = 36;                // Kdim / 64

// ---- workspace byte offsets
constexpr size_t B_H1H  = 0;
constexpr size_t HALO_BYTES = (size_t)Bsz * HPIX * 256 * 2;      // 8,921,088
constexpr size_t B_H2H  = B_H1H + HALO_BYTES;
constexpr size_t B_XTH  = B_H2H + HALO_BYTES;
constexpr size_t B_PROD = B_XTH + HALO_BYTES;
constexpr size_t B_OFFP = B_PROD + (size_t)NPIX * 4;
constexpr size_t B_WB2  = B_OFFP + (size_t)NPIX * 32 * 4;        // frag-packed (32-o tiles)
constexpr size_t B_WBD  = B_WB2 + (size_t)256 * Kdim * 2;        // frag-packed (32-o tiles)
constexpr size_t B_WB3  = B_WBD + (size_t)256 * Kdim * 2;        // linear (conv3g)

static __device__ __forceinline__ unsigned short f2bf(float f) {
    unsigned u = __builtin_bit_cast(unsigned, f);
    u += 0x7FFFu + ((u >> 16) & 1u);
    return (unsigned short)(u >> 16);
}
static __device__ __forceinline__ unsigned cvt_pk_bf16(float lo, float hi) {
    unsigned r;
    asm("v_cvt_pk_bf16_f32 %0, %1, %2" : "=v"(r) : "v"(lo), "v"(hi));
    return r;
}
static __device__ __forceinline__ f32x2 pk_mul(f32x2 a, f32x2 b) {
    f32x2 d;
    asm("v_pk_mul_f32 %0, %1, %2" : "=v"(d) : "v"(a), "v"(b));
    return d;
}
static __device__ __forceinline__ f32x2 pk_fma(f32x2 a, f32x2 b, f32x2 c) {
    f32x2 d;
    asm("v_pk_fma_f32 %0, %1, %2, %3" : "=v"(d) : "v"(a), "v"(b), "v"(c));
    return d;
}
static __device__ __forceinline__ f32x2 unpack2(unsigned u) {
    f32x2 v;
    v.x = __builtin_bit_cast(float, u << 16);
    v.y = __builtin_bit_cast(float, u & 0xFFFF0000u);
    return v;
}
static __device__ __forceinline__ void gload_lds16(const void* g, void* l) {
    __builtin_amdgcn_global_load_lds((const __attribute__((address_space(1))) unsigned int*)g,
                                     (__attribute__((address_space(3))) unsigned int*)l, 16, 0, 0);
}
static __device__ __forceinline__ int swz(int u) {
    return (((u & 7) ^ ((u >> 3) & 7)) << 3);
}

// ---------------------------------------------------------------- zero halo rings + prod
__global__ void k_zero_ring(unsigned short* h1h, unsigned short* h2h, unsigned short* xth,
                            float* prod) {
    int blk = blockIdx.x;
    if (blk >= 3120) {
        unsigned* p = (unsigned*)prod + (size_t)(blk - 3120) * 128 + threadIdx.x;
        *p = 0;
        return;
    }
    int img = blk / 260;
    int rp = blk - img * 260;
    int buf = img >> 2, b = img & 3;
    int y, x;
    if (rp < 66) { y = 0; x = rp; }
    else if (rp < 132) { y = 65; x = rp - 66; }
    else { int s2 = rp - 132; y = 1 + (s2 >> 1); x = (s2 & 1) * 65; }
    unsigned short* base = (buf == 0) ? h1h : (buf == 1) ? h2h : xth;
    unsigned* p = (unsigned*)(base + ((size_t)b * HPIX + y * HH + x) * 256);
    p[threadIdx.x] = 0;
}

// ---------------------------------------------------------------- fused: x_ref->xth transpose + prod partial
__global__ void k_prodx(const float* __restrict__ xr, const float* __restrict__ xn,
                        unsigned short* __restrict__ xth, float* __restrict__ prod) {
    __shared__ float t[32][33];
    __shared__ float red[8][33];
    int b = blockIdx.z;
    int c0 = blockIdx.y * 32;
    int y = blockIdx.x >> 1, x0 = (blockIdx.x & 1) * 32;
    int tx = threadIdx.x, ty = threadIdx.y;
    float part = 0.f;
#pragma unroll
    for (int i = 0; i < 32; i += 8) {
        size_t idx = ((size_t)b * 256 + c0 + ty + i) * HWp + y * Wwd + x0 + tx;
        float vr = xr[idx];
        float vn = xn[idx];
        t[ty + i][tx] = vr;
        part = fmaf(vr, vn, part);
    }
    red[ty][tx] = part;
    __syncthreads();
#pragma unroll
    for (int i = 0; i < 32; i += 8)
        xth[((size_t)b * HPIX + (y + 1) * HH + (x0 + ty + i + 1)) * 256 + c0 + tx] =
            f2bf(t[tx][ty + i]);
    if (ty == 0) {
        float s = red[0][tx] + red[1][tx] + red[2][tx] + red[3][tx] +
                  red[4][tx] + red[5][tx] + red[6][tx] + red[7][tx];
        atomicAdd(&prod[b * HWp + y * Wwd + x0 + tx], s);
    }
}

// ---------------------------------------------------------------- fused: corr (box3x3+leaky) + conv1 -> h1h
__global__ __launch_bounds__(256) void k_conv1c(const float* __restrict__ prod,
                                                const float* __restrict__ w1,
                                                const float* __restrict__ b1,
                                                unsigned short* __restrict__ h1h) {
    __shared__ float pp[5][36];
    __shared__ float pt[3][34];
    int px0 = blockIdx.x * 32;
    int b = px0 >> 12, y = (px0 & 4095) >> 6, x0 = px0 & 63;
    int tid = threadIdx.x;
    if (tid < 180) {
        int i = tid / 36, j = tid - i * 36;
        int yy = y - 2 + i, xx = x0 - 2 + j;
        float v = 0.f;
        if (yy >= 0 && yy < Hh && xx >= 0 && xx < Wwd) v = prod[b * HWp + yy * Wwd + xx];
        pp[i][j] = v;
    }
    __syncthreads();
    if (tid < 102) {
        int i = tid / 34, j = tid - i * 34;
        int yy = y - 1 + i, xx = x0 - 1 + j;
        float v = 0.f;
        if (yy >= 0 && yy < Hh && xx >= 0 && xx < Wwd) {
            float s = pp[i][j]     + pp[i][j + 1]     + pp[i][j + 2] +
                      pp[i + 1][j] + pp[i + 1][j + 1] + pp[i + 1][j + 2] +
                      pp[i + 2][j] + pp[i + 2][j + 1] + pp[i + 2][j + 2];
            s *= (1.0f / 256.0f);
            v = (s > 0.f) ? s : 0.1f * s;
        }
        pt[i][j] = v;
    }
    float wl[9];
#pragma unroll
    for (int k = 0; k < 9; ++k) wl[k] = w1[tid * 9 + k];
    float bias = b1[tid];
    __syncthreads();
    for (int p = 0; p < 32; ++p) {
        float acc = bias;
#pragma unroll
        for (int ky = 0; ky < 3; ++ky)
#pragma unroll
            for (int kx = 0; kx < 3; ++kx) acc = fmaf(pt[ky][p + kx], wl[ky * 3 + kx], acc);
        acc = fmaxf(acc, 0.f);
        h1h[((size_t)b * HPIX + (y + 1) * HH + (x0 + p + 1)) * 256 + tid] = f2bf(acc);
    }
}

// ---------------------------------------------------------------- all weight packs (32-o wave tiles, 8 tiles)
__global__ void k_packall(const float* __restrict__ w2, const float* __restrict__ wd,
                          const float* __restrict__ w3,
                          unsigned short* __restrict__ wb2f, unsigned short* __restrict__ wbdf,
                          unsigned short* __restrict__ wb3) {
    int blk = blockIdx.x;
    if (blk < 4608) {
        const float* w = (blk < 2304) ? w2 : wd;
        unsigned short* out = (blk < 2304) ? wb2f : wbdf;
        int i = (blk % 2304) * 256 + threadIdx.x;
        int e = i & 7;
        int lane = (i >> 3) & 63;
        int mi = (i >> 9) & 1;
        int kf = (i >> 10) & 1;
        int rest = i >> 11;                           // [0,288)
        int s = rest % 36;
        int wv = rest / 36;
        int o = wv * 32 + mi * 16 + (lane & 15);
        int kk = s * 64 + (kf * 4 + (lane >> 4)) * 8 + e;
        int c = kk & 255, tap = kk >> 8;
        out[i] = f2bf(w[((size_t)o * 256 + c) * 9 + tap]);
    } else {
        int i = (blk - 4608) * 256 + threadIdx.x;
        int o = i / Kdim;
        int r = i - o * Kdim;
        int k = r >> 8, c = r & 255;
        float v = (o < 18) ? w3[((size_t)o * 256 + c) * 9 + k] : 0.f;
        wb3[i] = f2bf(v);
    }
}

// ---------------------------------------------------------------- conv2 GEMM: 64px x 128o, 4 waves, 2 blocks/CU, ITER2
__global__ __launch_bounds__(256) void k_conv2g(const unsigned short* __restrict__ h1h,
                                                const unsigned short* __restrict__ wbf,
                                                const float* __restrict__ bias,
                                                unsigned short* __restrict__ h2h) {
    __shared__ short S_s[4][64 * 64];                 // 4 bufs, 32 KB
    const int tid = threadIdx.x;
    const int bid = blockIdx.x;
    const int lin = (bid & 7) * 64 + (bid >> 3);      // XCD-bijective, 512 blocks
    const int px0 = (lin >> 1) * 64;
    const int oblk = lin & 1;
    const int b = px0 >> 12;
    const unsigned short* hb = h1h + (size_t)b * HPIX * 256;
    const int pxl = tid >> 2;
    const int px = px0 + pxl;
    const int y = (px & 4095) >> 6, x = px & 63;
    const int u0 = (tid & 3) * 2;
    const int lane = tid & 63, wv = tid >> 6;
    const int ot = oblk * 4 + wv;                      // global 32-o tile
    const unsigned short* wfb = wbf + (size_t)ot * NSTEP * 2048 + lane * 8;
    const unsigned short* abase0 = hb + (size_t)((y + 1) * HH + (x + 1)) * 256 + u0 * 8;

    f32x4 acc[4][2] = {};
    u32x4 wA[2][4], wB[2][4];                          // [step-in-pair][kf*2+oi]
    u32x4 aP[4], aQ[4];                                // staged A: 2 steps x 2 units
    float bia[2];
#pragma unroll
    for (int oi = 0; oi < 2; ++oi) bia[oi] = bias[ot * 32 + oi * 16 + (lane & 15)];

    const int wr0 = pxl * 64 + ((u0 ^ (pxl & 7)) << 3);
    const int wr1 = pxl * 64 + (((u0 + 1) ^ (pxl & 7)) << 3);

    auto WLOAD = [&](int s, u32x4 (&wreg)[4]) {
#pragma unroll
        for (int f = 0; f < 4; ++f)
            wreg[f] = *(const u32x4*)(wfb + ((size_t)s * 4 + f) * 512);
    };
    auto ALOAD = [&](int s, u32x4& a0, u32x4& a1) {
        int tap = s >> 2, chunk = s & 3;
        int aoff = ((tap / 3 - 1) * HH + (tap % 3 - 1)) * 256 + chunk * 64;
        a0 = *(const u32x4*)(abase0 + aoff);
        a1 = *(const u32x4*)(abase0 + aoff + 8);
    };

    // prologue: steps 0,1 staged into bufs 0,1; steps 2,3 data in regs; W(0,1) loaded
    {
        u32x4 a0, a1, a2, a3;
        ALOAD(0, a0, a1);
        ALOAD(1, a2, a3);
        WLOAD(0, wA[0]);
        WLOAD(1, wA[1]);
        *(u32x4*)&S_s[0][wr0] = a0;
        *(u32x4*)&S_s[0][wr1] = a1;
        *(u32x4*)&S_s[1][wr0] = a2;
        *(u32x4*)&S_s[1][wr1] = a3;
        ALOAD(2, aP[0], aP[1]);
        ALOAD(3, aP[2], aP[3]);
        asm volatile("s_waitcnt lgkmcnt(0)" ::: "memory");
    }

    auto ITER2 = [&](int s, u32x4 (&wcur)[2][4], u32x4 (&wnxt)[2][4],
                     u32x4 (&aC)[4], u32x4 (&aN)[4], short* SBc, short* SBn) {
        __builtin_amdgcn_s_barrier();
        __builtin_amdgcn_sched_barrier(0);
        if (s + 2 < NSTEP) {                           // stage steps s+2,s+3 (data 1 iter old)
            *(u32x4*)&SBn[wr0] = aC[0];
            *(u32x4*)&SBn[wr1] = aC[1];
            *(u32x4*)&SBn[64 * 64 + wr0] = aC[2];
            *(u32x4*)&SBn[64 * 64 + wr1] = aC[3];
        }
        if (s + 4 < NSTEP) {                           // issue 2 steps further ahead
            ALOAD(s + 4, aN[0], aN[1]);
            ALOAD(s + 5, aN[2], aN[3]);
        }
        if (s + 2 < NSTEP) {
            WLOAD(s + 2, wnxt[0]);
            WLOAD(s + 3, wnxt[1]);
        }
#pragma unroll
        for (int half = 0; half < 2; ++half) {
            const short* SB = SBc + half * 64 * 64;
            short8v af[4][2];
#pragma unroll
            for (int pi = 0; pi < 4; ++pi) {
                int row = pi * 16 + (lane & 15);
#pragma unroll
                for (int kf = 0; kf < 2; ++kf) {
                    int c8 = kf * 4 + (lane >> 4);
                    af[pi][kf] = *(const short8v*)&SB[row * 64 + ((c8 ^ (row & 7)) << 3)];
                }
            }
            __builtin_amdgcn_s_setprio(1);
#pragma unroll
            for (int kf = 0; kf < 2; ++kf)
#pragma unroll
                for (int pi = 0; pi < 4; ++pi)
#pragma unroll
                    for (int oi = 0; oi < 2; ++oi)
                        acc[pi][oi] = __builtin_amdgcn_mfma_f32_16x16x32_bf16(
                            af[pi][kf], __builtin_bit_cast(short8v, wcur[half][kf * 2 + oi]),
                            acc[pi][oi], 0, 0, 0);
            __builtin_amdgcn_s_setprio(0);
        }
        asm volatile("s_waitcnt lgkmcnt(0)" ::: "memory");
    };

    for (int s4 = 0; s4 < NSTEP; s4 += 4) {
        ITER2(s4, wA, wB, aP, aQ, &S_s[0][0], &S_s[2][0]);
        ITER2(s4 + 2, wB, wA, aQ, aP, &S_s[2][0], &S_s[0][0]);
    }

#pragma unroll
    for (int pi = 0; pi < 4; ++pi) {
#pragma unroll
        for (int j = 0; j < 4; ++j) {
            int p2 = px0 + pi * 16 + (lane >> 4) * 4 + j;
            int yy = (p2 & 4095) >> 6, xx = p2 & 63;
            unsigned short* dst = h2h + ((size_t)b * HPIX + (yy + 1) * HH + (xx + 1)) * 256;
#pragma unroll
            for (int oi = 0; oi < 2; ++oi) {
                int o = ot * 32 + oi * 16 + (lane & 15);
                dst[o] = f2bf(fmaxf(acc[pi][oi][j] + bia[oi], 0.f));
            }
        }
    }
}

// ---------------------------------------------------------------- conv3 GEMM: 64px x 32o, BK=64, dbuf
__global__ __launch_bounds__(256) void k_conv3g(const unsigned short* __restrict__ h2h,
                                                const unsigned short* __restrict__ wb,
                                                const float* __restrict__ bias,
                                                float* __restrict__ offp) {
    __shared__ short A_s[2][64 * 64];
    __shared__ short B_s[2][32 * 64];
    const int tid = threadIdx.x;
    const int px0 = blockIdx.x * 64;
    const int b = px0 >> 12;
    const unsigned short* hb = h2h + (size_t)b * HPIX * 256;

    const unsigned short* abase[2];
#pragma unroll
    for (int i = 0; i < 2; ++i) {
        int u = i * 256 + tid;
        int pxl = u >> 3;
        int pxg = px0 + pxl;
        int y = (pxg & 4095) >> 6, x = pxg & 63;
        abase[i] = hb + (size_t)((y + 1) * HH + (x + 1)) * 256 + swz(u);
    }
    const unsigned short* bbase = wb + (size_t)(tid >> 3) * Kdim + swz(tid);

    const int lane = tid & 63, wv = tid >> 6;
    f32x4 acc[2] = {};

    auto STAGE = [&](int s, int buf) {
        int tap = s >> 2, chunk = s & 3;
        int delta = ((tap / 3 - 1) * HH + (tap % 3 - 1)) * 256 + chunk * 64;
        short* Ab = &A_s[buf][0];
#pragma unroll
        for (int i = 0; i < 2; ++i) gload_lds16(abase[i] + delta, Ab + (i * 256 + tid) * 8);
        gload_lds16(bbase + s * 64, &B_s[buf][tid * 8]);
    };

    STAGE(0, 0);
    __syncthreads();
    for (int s = 0; s < NSTEP; ++s) {
        int cur = s & 1;
        if (s + 1 < NSTEP) STAGE(s + 1, cur ^ 1);
        const short* Ab = &A_s[cur][0];
        const short* Bb = &B_s[cur][0];
        short8v af[2], bf[2][2];
#pragma unroll
        for (int kf = 0; kf < 2; ++kf) {
            int row = wv * 16 + (lane & 15);
            int c8 = kf * 4 + (lane >> 4);
            af[kf] = *(const short8v*)&Ab[row * 64 + ((c8 ^ (row & 7)) << 3)];
        }
#pragma unroll
        for (int ni = 0; ni < 2; ++ni) {
            int row = ni * 16 + (lane & 15);
#pragma unroll
            for (int kf = 0; kf < 2; ++kf) {
                int c8 = kf * 4 + (lane >> 4);
                bf[ni][kf] = *(const short8v*)&B_s[cur][row * 64 + ((c8 ^ (row & 7)) << 3)];
            }
        }
#pragma unroll
        for (int kf = 0; kf < 2; ++kf)
#pragma unroll
            for (int ni = 0; ni < 2; ++ni)
                acc[ni] = __builtin_amdgcn_mfma_f32_16x16x32_bf16(af[kf], bf[ni][kf], acc[ni], 0, 0, 0);
        __syncthreads();
    }
#pragma unroll
    for (int j = 0; j < 4; ++j) {
        int px = px0 + wv * 16 + (lane >> 4) * 4 + j;
#pragma unroll
        for (int ni = 0; ni < 2; ++ni) {
            int o = ni * 16 + (lane & 15);
            float bv = (o < 18) ? bias[o] : 0.f;
            offp[(size_t)px * 32 + o] = fmaxf(acc[ni][j] + bv, 0.f);
        }
    }
}

// ---------------------------------------------------------------- dcn GEMM: 64px x 256o, 8 waves, ITER2 (R11)
__global__ __launch_bounds__(512) void k_dcng(const unsigned short* __restrict__ xth,
                                              const float* __restrict__ offp,
                                              const unsigned short* __restrict__ wbf,
                                              const float* __restrict__ xn,
                                              float* __restrict__ out) {
    __shared__ short S_s[4][64 * 64];                 // 4 bufs, 32 KB
    const int tid = threadIdx.x;
    const int bid = blockIdx.x;
    const int px0 = ((bid & 7) * 32 + (bid >> 3)) * 64;   // XCD-bijective
    const int b = px0 >> 12;
    const unsigned short* xb = xth + (size_t)b * HPIX * 256;
    const int pxl = tid >> 3;
    const int px = px0 + pxl;
    const int y = (px & 4095) >> 6, x = px & 63;
    const int u0 = tid & 7;
    const int lane = tid & 63, wv = tid >> 6;
    const unsigned short* wfb = wbf + (size_t)wv * NSTEP * 2048 + lane * 8;
    const float2* offv = (const float2*)offp;

    f32x4 acc[2][4] = {};
    u32x4 wA[2][4], wB[2][4];
    u32x4 g[2][4];
    const int wr0 = pxl * 64 + ((u0 ^ (pxl & 7)) << 3);

    const unsigned short* pcorner[4];
    f32x2 wpair[4];
    float2 offn;

    auto SETUP = [&](int tap, float dyo, float dxo) {
        int ky = tap / 3 - 1, kx = tap % 3 - 1;
        float ypos = (float)(y + ky) + dyo;
        float xpos = (float)(x + kx) + dxo;
        float y0f = floorf(ypos), x0f = floorf(xpos);
        float wy = ypos - y0f, wx = xpos - x0f;
        int y0 = (int)y0f, x0 = (int)x0f;
        bool y0v = (y0 >= 0) && (y0 < Hh), y1v = (y0 + 1 >= 0) && (y0 + 1 < Hh);
        bool x0v = (x0 >= 0) && (x0 < Wwd), x1v = (x0 + 1 >= 0) && (x0 + 1 < Wwd);
        int hy0 = min(max(y0, -1), 64) + 1, hy1 = min(max(y0 + 1, -1), 64) + 1;
        int hx0 = min(max(x0, -1), 64) + 1, hx1 = min(max(x0 + 1, -1), 64) + 1;
        float w0 = (1.f - wy) * (1.f - wx) * (float)(y0v && x0v);
        float w1 = (1.f - wy) * wx * (float)(y0v && x1v);
        float w2 = wy * (1.f - wx) * (float)(y1v && x0v);
        float w3 = wy * wx * (float)(y1v && x1v);
        wpair[0] = (f32x2){w0, w0};
        wpair[1] = (f32x2){w1, w1};
        wpair[2] = (f32x2){w2, w2};
        wpair[3] = (f32x2){w3, w3};
        pcorner[0] = xb + (size_t)((hy0 * HH + hx0) * 256) + u0 * 8;
        pcorner[1] = xb + (size_t)((hy0 * HH + hx1) * 256) + u0 * 8;
        pcorner[2] = xb + (size_t)((hy1 * HH + hx0) * 256) + u0 * 8;
        pcorner[3] = xb + (size_t)((hy1 * HH + hx1) * 256) + u0 * 8;
    };
    auto WLOAD = [&](int s, u32x4 (&wreg)[4]) {
#pragma unroll
        for (int f = 0; f < 4; ++f)
            wreg[f] = *(const u32x4*)(wfb + ((size_t)s * 4 + f) * 512);
    };
    auto GISSUE = [&](int s, u32x4 (&gr)[4]) {
        const int nco = (s & 3) * 64;
#pragma unroll
        for (int c = 0; c < 4; ++c) gr[c] = *(const u32x4*)(pcorner[c] + nco);
    };
    auto COMBINE_WRITE = [&](u32x4 (&gr)[4], short* SBn) {
        u32x4 res;
#pragma unroll
        for (int qd = 0; qd < 4; ++qd) {
            f32x2 a = pk_mul(unpack2(gr[0][qd]), wpair[0]);
            a = pk_fma(unpack2(gr[1][qd]), wpair[1], a);
            a = pk_fma(unpack2(gr[2][qd]), wpair[2], a);
            a = pk_fma(unpack2(gr[3][qd]), wpair[3], a);
            res[qd] = cvt_pk_bf16(a.x, a.y);
        }
        *(u32x4*)&SBn[wr0] = res;
    };

    // prologue
    {
        float2 o0 = offv[(size_t)px * 16];
        SETUP(0, o0.x, o0.y);
        u32x4 g0[4], g1[4];
        GISSUE(0, g0);
        GISSUE(1, g1);
        WLOAD(0, wA[0]);
        WLOAD(1, wA[1]);
        COMBINE_WRITE(g0, &S_s[0][0]);
        COMBINE_WRITE(g1, &S_s[1][0]);
        GISSUE(2, g[0]);
        GISSUE(3, g[1]);
        offn = offv[(size_t)px * 16 + 1];
        asm volatile("s_waitcnt lgkmcnt(0)" ::: "memory");
    }

    auto ITER2 = [&](int s, u32x4 (&wcur)[2][4], u32x4 (&wnxt)[2][4], short* SBc, short* SBn) {
        __builtin_amdgcn_s_barrier();
        __builtin_amdgcn_sched_barrier(0);
        if (s + 2 < NSTEP) {
            COMBINE_WRITE(g[0], SBn);
            COMBINE_WRITE(g[1], SBn + 64 * 64);
        }
        if ((s & 3) == 0 && s + 4 < NSTEP)
            SETUP((s + 4) >> 2, offn.x, offn.y);
        if ((s & 3) == 2 && ((s + 8) >> 2) < 9)
            offn = offv[(size_t)px * 16 + ((s + 8) >> 2)];
        if (s + 4 < NSTEP) {
            GISSUE(s + 4, g[0]);
            GISSUE(s + 5, g[1]);
        }
        if (s + 2 < NSTEP) {
            WLOAD(s + 2, wnxt[0]);
            WLOAD(s + 3, wnxt[1]);
        }
#pragma unroll
        for (int half = 0; half < 2; ++half) {
            const short* SB = SBc + half * 64 * 64;
            short8v sf[4][2];
#pragma unroll
            for (int ni = 0; ni < 4; ++ni) {
                int row = ni * 16 + (lane & 15);
#pragma unroll
                for (int kf = 0; kf < 2; ++kf) {
                    int c8 = kf * 4 + (lane >> 4);
                    sf[ni][kf] = *(const short8v*)&SB[row * 64 + ((c8 ^ (row & 7)) << 3)];
                }
            }
            __builtin_amdgcn_s_setprio(1);
#pragma unroll
            for (int kf = 0; kf < 2; ++kf)
#pragma unroll
                for (int mi = 0; mi < 2; ++mi)
#pragma unroll
                    for (int ni = 0; ni < 4; ++ni)
                        acc[mi][ni] = __builtin_amdgcn_mfma_f32_16x16x32_bf16(
                            __builtin_bit_cast(short8v, wcur[half][kf * 2 + mi]), sf[ni][kf],
                            acc[mi][ni], 0, 0, 0);
            __builtin_amdgcn_s_setprio(0);
        }
        asm volatile("s_waitcnt lgkmcnt(0)" ::: "memory");
    };

    for (int s4 = 0; s4 < NSTEP; s4 += 4) {
        ITER2(s4, wA, wB, &S_s[0][0], &S_s[2][0]);
        ITER2(s4 + 2, wB, wA, &S_s[2][0], &S_s[0][0]);
    }

#pragma unroll
    for (int mi = 0; mi < 2; ++mi) {
        int o = wv * 32 + mi * 16 + (lane >> 4) * 4;
#pragma unroll
        for (int j = 0; j < 4; ++j) {
            size_t rowbase = ((size_t)b * 256 + o + j) * HWp;
#pragma unroll
            for (int ni = 0; ni < 4; ++ni) {
                int p2 = (px0 + ni * 16 + (lane & 15)) & 4095;
                size_t idx = rowbase + p2;
                out[idx] = 0.5f * (xn[idx] + fmaxf(acc[mi][ni][j], 0.f));
            }
        }
    }
}

extern "C" void kernel_launch(void* const* d_in, const int* in_sizes, int n_in,
                              void* d_out, int out_size, void* d_ws, size_t ws_size,
                              hipStream_t stream) {
    const float* x_ref  = (const float*)d_in[0];
    const float* x_next = (const float*)d_in[1];
    const float* w1 = (const float*)d_in[2];
    const float* b1 = (const float*)d_in[3];
    const float* w2 = (const float*)d_in[4];
    const float* b2 = (const float*)d_in[5];
    const float* w3 = (const float*)d_in[6];
    const float* b3 = (const float*)d_in[7];
    const float* wd = (const float*)d_in[8];
    float* out = (float*)d_out;
    char* ws = (char*)d_ws;

    unsigned short* h1h = (unsigned short*)(ws + B_H1H);
    unsigned short* h2h = (unsigned short*)(ws + B_H2H);
    unsigned short* xth = (unsigned short*)(ws + B_XTH);
    float* prod = (float*)(ws + B_PROD);
    float* offp = (float*)(ws + B_OFFP);
    unsigned short* wb2f = (unsigned short*)(ws + B_WB2);
    unsigned short* wbdf = (unsigned short*)(ws + B_WBD);
    unsigned short* wb3  = (unsigned short*)(ws + B_WB3);

    k_zero_ring<<<3120 + 128, 128, 0, stream>>>(h1h, h2h, xth, prod);
    k_prodx<<<dim3(128, 8, Bsz), dim3(32, 8), 0, stream>>>(x_ref, x_next, xth, prod);
    k_packall<<<4896, 256, 0, stream>>>(w2, wd, w3, wb2f, wbdf, wb3);
    k_conv1c<<<NPIX / 32, 256, 0, stream>>>(prod, w1, b1, h1h);
    k_conv2g<<<512, 256, 0, stream>>>(h1h, wb2f, b2, h2h);
    k_conv3g<<<256, 256, 0, stream>>>(h2h, wb3, b3, offp);
    k_dcng<<<256, 512, 0, stream>>>(xth, offp, wbdf, x_next, out);
}

// Round 14
// 97.486 us; speedup vs baseline: 1.2872x; 1.1024x over previous
//
#include <hip/hip_runtime.h>

typedef __attribute__((ext_vector_type(8))) short short8v;
typedef __attribute__((ext_vector_type(4))) float f32x4;
typedef __attribute__((ext_vector_type(2))) float f32x2;
typedef __attribute__((ext_vector_type(4))) unsigned int u32x4;

constexpr int Bsz = 4;
constexpr int Hh = 64, Wwd = 64;
constexpr int HWp = Hh * Wwd;            // 4096
constexpr int NPIX = Bsz * HWp;          // 16384
constexpr int HH = 66;                   // halo dim
constexpr int HPIX = HH * HH;            // 4356
constexpr int Kdim = 2304;               // 9*256
constexpr int NSTEP = 36;                // Kdim / 64

// ---- workspace byte offsets
constexpr size_t B_H1H  = 0;
constexpr size_t HALO_BYTES = (size_t)Bsz * HPIX * 256 * 2;      // 8,921,088
constexpr size_t B_H2H  = B_H1H + HALO_BYTES;
constexpr size_t B_XTH  = B_H2H + HALO_BYTES;
constexpr size_t B_PROD = B_XTH + HALO_BYTES;
constexpr size_t B_OFFP = B_PROD + (size_t)NPIX * 4;
constexpr size_t B_WB2  = B_OFFP + (size_t)NPIX * 32 * 4;        // frag-packed (32-o tiles)
constexpr size_t B_WBD  = B_WB2 + (size_t)256 * Kdim * 2;        // frag-packed (32-o tiles)
constexpr size_t B_WB3  = B_WBD + (size_t)256 * Kdim * 2;        // frag-packed (one 32-o tile)

static __device__ __forceinline__ unsigned short f2bf(float f) {
    unsigned u = __builtin_bit_cast(unsigned, f);
    u += 0x7FFFu + ((u >> 16) & 1u);
    return (unsigned short)(u >> 16);
}
static __device__ __forceinline__ unsigned cvt_pk_bf16(float lo, float hi) {
    unsigned r;
    asm("v_cvt_pk_bf16_f32 %0, %1, %2" : "=v"(r) : "v"(lo), "v"(hi));
    return r;
}
static __device__ __forceinline__ f32x2 pk_mul(f32x2 a, f32x2 b) {
    f32x2 d;
    asm("v_pk_mul_f32 %0, %1, %2" : "=v"(d) : "v"(a), "v"(b));
    return d;
}
static __device__ __forceinline__ f32x2 pk_fma(f32x2 a, f32x2 b, f32x2 c) {
    f32x2 d;
    asm("v_pk_fma_f32 %0, %1, %2, %3" : "=v"(d) : "v"(a), "v"(b), "v"(c));
    return d;
}
static __device__ __forceinline__ f32x2 unpack2(unsigned u) {
    f32x2 v;
    v.x = __builtin_bit_cast(float, u << 16);
    v.y = __builtin_bit_cast(float, u & 0xFFFF0000u);
    return v;
}
static __device__ __forceinline__ int swz(int u) {
    return (((u & 7) ^ ((u >> 3) & 7)) << 3);
}

// ---------------------------------------------------------------- zero halo rings + prod
__global__ void k_zero_ring(unsigned short* h1h, unsigned short* h2h, unsigned short* xth,
                            float* prod) {
    int blk = blockIdx.x;
    if (blk >= 3120) {
        unsigned* p = (unsigned*)prod + (size_t)(blk - 3120) * 128 + threadIdx.x;
        *p = 0;
        return;
    }
    int img = blk / 260;
    int rp = blk - img * 260;
    int buf = img >> 2, b = img & 3;
    int y, x;
    if (rp < 66) { y = 0; x = rp; }
    else if (rp < 132) { y = 65; x = rp - 66; }
    else { int s2 = rp - 132; y = 1 + (s2 >> 1); x = (s2 & 1) * 65; }
    unsigned short* base = (buf == 0) ? h1h : (buf == 1) ? h2h : xth;
    unsigned* p = (unsigned*)(base + ((size_t)b * HPIX + y * HH + x) * 256);
    p[threadIdx.x] = 0;
}

// ---------------------------------------------------------------- fused: x_ref->xth transpose + prod partial
__global__ void k_prodx(const float* __restrict__ xr, const float* __restrict__ xn,
                        unsigned short* __restrict__ xth, float* __restrict__ prod) {
    __shared__ float t[32][33];
    __shared__ float red[8][33];
    int b = blockIdx.z;
    int c0 = blockIdx.y * 32;
    int y = blockIdx.x >> 1, x0 = (blockIdx.x & 1) * 32;
    int tx = threadIdx.x, ty = threadIdx.y;
    float part = 0.f;
#pragma unroll
    for (int i = 0; i < 32; i += 8) {
        size_t idx = ((size_t)b * 256 + c0 + ty + i) * HWp + y * Wwd + x0 + tx;
        float vr = xr[idx];
        float vn = xn[idx];
        t[ty + i][tx] = vr;
        part = fmaf(vr, vn, part);
    }
    red[ty][tx] = part;
    __syncthreads();
#pragma unroll
    for (int i = 0; i < 32; i += 8)
        xth[((size_t)b * HPIX + (y + 1) * HH + (x0 + ty + i + 1)) * 256 + c0 + tx] =
            f2bf(t[tx][ty + i]);
    if (ty == 0) {
        float s = red[0][tx] + red[1][tx] + red[2][tx] + red[3][tx] +
                  red[4][tx] + red[5][tx] + red[6][tx] + red[7][tx];
        atomicAdd(&prod[b * HWp + y * Wwd + x0 + tx], s);
    }
}

// ---------------------------------------------------------------- fused: corr (box3x3+leaky) + conv1 -> h1h
__global__ __launch_bounds__(256) void k_conv1c(const float* __restrict__ prod,
                                                const float* __restrict__ w1,
                                                const float* __restrict__ b1,
                                                unsigned short* __restrict__ h1h) {
    __shared__ float pp[5][36];
    __shared__ float pt[3][34];
    int px0 = blockIdx.x * 32;
    int b = px0 >> 12, y = (px0 & 4095) >> 6, x0 = px0 & 63;
    int tid = threadIdx.x;
    if (tid < 180) {
        int i = tid / 36, j = tid - i * 36;
        int yy = y - 2 + i, xx = x0 - 2 + j;
        float v = 0.f;
        if (yy >= 0 && yy < Hh && xx >= 0 && xx < Wwd) v = prod[b * HWp + yy * Wwd + xx];
        pp[i][j] = v;
    }
    __syncthreads();
    if (tid < 102) {
        int i = tid / 34, j = tid - i * 34;
        int yy = y - 1 + i, xx = x0 - 1 + j;
        float v = 0.f;
        if (yy >= 0 && yy < Hh && xx >= 0 && xx < Wwd) {
            float s = pp[i][j]     + pp[i][j + 1]     + pp[i][j + 2] +
                      pp[i + 1][j] + pp[i + 1][j + 1] + pp[i + 1][j + 2] +
                      pp[i + 2][j] + pp[i + 2][j + 1] + pp[i + 2][j + 2];
            s *= (1.0f / 256.0f);
            v = (s > 0.f) ? s : 0.1f * s;
        }
        pt[i][j] = v;
    }
    float wl[9];
#pragma unroll
    for (int k = 0; k < 9; ++k) wl[k] = w1[tid * 9 + k];
    float bias = b1[tid];
    __syncthreads();
    for (int p = 0; p < 32; ++p) {
        float acc = bias;
#pragma unroll
        for (int ky = 0; ky < 3; ++ky)
#pragma unroll
            for (int kx = 0; kx < 3; ++kx) acc = fmaf(pt[ky][p + kx], wl[ky * 3 + kx], acc);
        acc = fmaxf(acc, 0.f);
        h1h[((size_t)b * HPIX + (y + 1) * HH + (x0 + p + 1)) * 256 + tid] = f2bf(acc);
    }
}

// ---------------------------------------------------------------- all weight packs
// [0,2304): wb2f 32-o frag; [2304,4608): wbdf 32-o frag; [4608,4896): wb3f single-32-o frag.
__global__ void k_packall(const float* __restrict__ w2, const float* __restrict__ wd,
                          const float* __restrict__ w3,
                          unsigned short* __restrict__ wb2f, unsigned short* __restrict__ wbdf,
                          unsigned short* __restrict__ wb3f) {
    int blk = blockIdx.x;
    if (blk < 4608) {
        const float* w = (blk < 2304) ? w2 : wd;
        unsigned short* out = (blk < 2304) ? wb2f : wbdf;
        int i = (blk % 2304) * 256 + threadIdx.x;
        int e = i & 7;
        int lane = (i >> 3) & 63;
        int mi = (i >> 9) & 1;
        int kf = (i >> 10) & 1;
        int rest = i >> 11;                           // [0,288)
        int s = rest % 36;
        int wv = rest / 36;
        int o = wv * 32 + mi * 16 + (lane & 15);
        int kk = s * 64 + (kf * 4 + (lane >> 4)) * 8 + e;
        int c = kk & 255, tap = kk >> 8;
        out[i] = f2bf(w[((size_t)o * 256 + c) * 9 + tap]);
    } else {
        // conv3 frag-pack: idx = ((s*4 + kf*2 + oi)*64 + lane)*8 + e, 73728 elems (288 blocks)
        int i = (blk - 4608) * 256 + threadIdx.x;
        int e = i & 7;
        int lane = (i >> 3) & 63;
        int oi = (i >> 9) & 1;
        int kf = (i >> 10) & 1;
        int s = i >> 11;                              // [0,36)
        int o = oi * 16 + (lane & 15);
        int kk = s * 64 + (kf * 4 + (lane >> 4)) * 8 + e;
        int c = kk & 255, tap = kk >> 8;
        float v = (o < 18) ? w3[((size_t)o * 256 + c) * 9 + tap] : 0.f;
        wb3f[i] = f2bf(v);
    }
}

// ---------------------------------------------------------------- conv2 GEMM: 64px x 128o, 4 waves, 2 blocks/CU, ITER2
__global__ __launch_bounds__(256) void k_conv2g(const unsigned short* __restrict__ h1h,
                                                const unsigned short* __restrict__ wbf,
                                                const float* __restrict__ bias,
                                                unsigned short* __restrict__ h2h) {
    __shared__ short S_s[4][64 * 64];                 // 4 bufs, 32 KB
    const int tid = threadIdx.x;
    const int bid = blockIdx.x;
    const int lin = (bid & 7) * 64 + (bid >> 3);      // XCD-bijective, 512 blocks
    const int px0 = (lin >> 1) * 64;
    const int oblk = lin & 1;
    const int b = px0 >> 12;
    const unsigned short* hb = h1h + (size_t)b * HPIX * 256;
    const int pxl = tid >> 2;
    const int px = px0 + pxl;
    const int y = (px & 4095) >> 6, x = px & 63;
    const int u0 = (tid & 3) * 2;
    const int lane = tid & 63, wv = tid >> 6;
    const int ot = oblk * 4 + wv;                      // global 32-o tile
    const unsigned short* wfb = wbf + (size_t)ot * NSTEP * 2048 + lane * 8;
    const unsigned short* abase0 = hb + (size_t)((y + 1) * HH + (x + 1)) * 256 + u0 * 8;

    f32x4 acc[4][2] = {};
    u32x4 wA[2][4], wB[2][4];
    u32x4 aP[4], aQ[4];
    float bia[2];
#pragma unroll
    for (int oi = 0; oi < 2; ++oi) bia[oi] = bias[ot * 32 + oi * 16 + (lane & 15)];

    const int wr0 = pxl * 64 + ((u0 ^ (pxl & 7)) << 3);
    const int wr1 = pxl * 64 + (((u0 + 1) ^ (pxl & 7)) << 3);

    auto WLOAD = [&](int s, u32x4 (&wreg)[4]) {
#pragma unroll
        for (int f = 0; f < 4; ++f)
            wreg[f] = *(const u32x4*)(wfb + ((size_t)s * 4 + f) * 512);
    };
    auto ALOAD = [&](int s, u32x4& a0, u32x4& a1) {
        int tap = s >> 2, chunk = s & 3;
        int aoff = ((tap / 3 - 1) * HH + (tap % 3 - 1)) * 256 + chunk * 64;
        a0 = *(const u32x4*)(abase0 + aoff);
        a1 = *(const u32x4*)(abase0 + aoff + 8);
    };

    {
        u32x4 a0, a1, a2, a3;
        ALOAD(0, a0, a1);
        ALOAD(1, a2, a3);
        WLOAD(0, wA[0]);
        WLOAD(1, wA[1]);
        *(u32x4*)&S_s[0][wr0] = a0;
        *(u32x4*)&S_s[0][wr1] = a1;
        *(u32x4*)&S_s[1][wr0] = a2;
        *(u32x4*)&S_s[1][wr1] = a3;
        ALOAD(2, aP[0], aP[1]);
        ALOAD(3, aP[2], aP[3]);
        asm volatile("s_waitcnt lgkmcnt(0)" ::: "memory");
    }

    auto ITER2 = [&](int s, u32x4 (&wcur)[2][4], u32x4 (&wnxt)[2][4],
                     u32x4 (&aC)[4], u32x4 (&aN)[4], short* SBc, short* SBn) {
        __builtin_amdgcn_s_barrier();
        __builtin_amdgcn_sched_barrier(0);
        if (s + 2 < NSTEP) {
            *(u32x4*)&SBn[wr0] = aC[0];
            *(u32x4*)&SBn[wr1] = aC[1];
            *(u32x4*)&SBn[64 * 64 + wr0] = aC[2];
            *(u32x4*)&SBn[64 * 64 + wr1] = aC[3];
        }
        if (s + 4 < NSTEP) {
            ALOAD(s + 4, aN[0], aN[1]);
            ALOAD(s + 5, aN[2], aN[3]);
        }
        if (s + 2 < NSTEP) {
            WLOAD(s + 2, wnxt[0]);
            WLOAD(s + 3, wnxt[1]);
        }
#pragma unroll
        for (int half = 0; half < 2; ++half) {
            const short* SB = SBc + half * 64 * 64;
            short8v af[4][2];
#pragma unroll
            for (int pi = 0; pi < 4; ++pi) {
                int row = pi * 16 + (lane & 15);
#pragma unroll
                for (int kf = 0; kf < 2; ++kf) {
                    int c8 = kf * 4 + (lane >> 4);
                    af[pi][kf] = *(const short8v*)&SB[row * 64 + ((c8 ^ (row & 7)) << 3)];
                }
            }
            __builtin_amdgcn_s_setprio(1);
#pragma unroll
            for (int kf = 0; kf < 2; ++kf)
#pragma unroll
                for (int pi = 0; pi < 4; ++pi)
#pragma unroll
                    for (int oi = 0; oi < 2; ++oi)
                        acc[pi][oi] = __builtin_amdgcn_mfma_f32_16x16x32_bf16(
                            af[pi][kf], __builtin_bit_cast(short8v, wcur[half][kf * 2 + oi]),
                            acc[pi][oi], 0, 0, 0);
            __builtin_amdgcn_s_setprio(0);
        }
        asm volatile("s_waitcnt lgkmcnt(0)" ::: "memory");
    };

    for (int s4 = 0; s4 < NSTEP; s4 += 4) {
        ITER2(s4, wA, wB, aP, aQ, &S_s[0][0], &S_s[2][0]);
        ITER2(s4 + 2, wB, wA, aQ, aP, &S_s[2][0], &S_s[0][0]);
    }

#pragma unroll
    for (int pi = 0; pi < 4; ++pi) {
#pragma unroll
        for (int j = 0; j < 4; ++j) {
            int p2 = px0 + pi * 16 + (lane >> 4) * 4 + j;
            int yy = (p2 & 4095) >> 6, xx = p2 & 63;
            unsigned short* dst = h2h + ((size_t)b * HPIX + (yy + 1) * HH + (xx + 1)) * 256;
#pragma unroll
            for (int oi = 0; oi < 2; ++oi) {
                int o = ot * 32 + oi * 16 + (lane & 15);
                dst[o] = f2bf(fmaxf(acc[pi][oi][j] + bia[oi], 0.f));
            }
        }
    }
}

// ---------------------------------------------------------------- conv3 GEMM: 64px x 32o, 4 waves (16px each), ITER2
__global__ __launch_bounds__(256) void k_conv3g(const unsigned short* __restrict__ h2h,
                                                const unsigned short* __restrict__ wb3f,
                                                const float* __restrict__ bias,
                                                float* __restrict__ offp) {
    __shared__ short S_s[4][64 * 64];                 // 4 bufs, 32 KB
    const int tid = threadIdx.x;
    const int bid = blockIdx.x;
    const int px0 = ((bid & 7) * 32 + (bid >> 3)) * 64;   // XCD-bijective, 256 blocks
    const int b = px0 >> 12;
    const unsigned short* hb = h2h + (size_t)b * HPIX * 256;
    const int pxl = tid >> 2;
    const int px = px0 + pxl;
    const int y = (px & 4095) >> 6, x = px & 63;
    const int u0 = (tid & 3) * 2;
    const int lane = tid & 63, wv = tid >> 6;
    const unsigned short* wfb = wb3f + lane * 8;
    const unsigned short* abase0 = hb + (size_t)((y + 1) * HH + (x + 1)) * 256 + u0 * 8;

    f32x4 acc[2] = {};
    u32x4 wA[2][4], wB[2][4];
    u32x4 aP[4], aQ[4];
    float bia[2];
#pragma unroll
    for (int oi = 0; oi < 2; ++oi) {
        int o = oi * 16 + (lane & 15);
        bia[oi] = (o < 18) ? bias[o] : 0.f;
    }

    const int wr0 = pxl * 64 + ((u0 ^ (pxl & 7)) << 3);
    const int wr1 = pxl * 64 + (((u0 + 1) ^ (pxl & 7)) << 3);

    auto WLOAD = [&](int s, u32x4 (&wreg)[4]) {
#pragma unroll
        for (int f = 0; f < 4; ++f)
            wreg[f] = *(const u32x4*)(wfb + ((size_t)s * 4 + f) * 512);
    };
    auto ALOAD = [&](int s, u32x4& a0, u32x4& a1) {
        int tap = s >> 2, chunk = s & 3;
        int aoff = ((tap / 3 - 1) * HH + (tap % 3 - 1)) * 256 + chunk * 64;
        a0 = *(const u32x4*)(abase0 + aoff);
        a1 = *(const u32x4*)(abase0 + aoff + 8);
    };

    {
        u32x4 a0, a1, a2, a3;
        ALOAD(0, a0, a1);
        ALOAD(1, a2, a3);
        WLOAD(0, wA[0]);
        WLOAD(1, wA[1]);
        *(u32x4*)&S_s[0][wr0] = a0;
        *(u32x4*)&S_s[0][wr1] = a1;
        *(u32x4*)&S_s[1][wr0] = a2;
        *(u32x4*)&S_s[1][wr1] = a3;
        ALOAD(2, aP[0], aP[1]);
        ALOAD(3, aP[2], aP[3]);
        asm volatile("s_waitcnt lgkmcnt(0)" ::: "memory");
    }

    auto ITER2 = [&](int s, u32x4 (&wcur)[2][4], u32x4 (&wnxt)[2][4],
                     u32x4 (&aC)[4], u32x4 (&aN)[4], short* SBc, short* SBn) {
        __builtin_amdgcn_s_barrier();
        __builtin_amdgcn_sched_barrier(0);
        if (s + 2 < NSTEP) {
            *(u32x4*)&SBn[wr0] = aC[0];
            *(u32x4*)&SBn[wr1] = aC[1];
            *(u32x4*)&SBn[64 * 64 + wr0] = aC[2];
            *(u32x4*)&SBn[64 * 64 + wr1] = aC[3];
        }
        if (s + 4 < NSTEP) {
            ALOAD(s + 4, aN[0], aN[1]);
            ALOAD(s + 5, aN[2], aN[3]);
        }
        if (s + 2 < NSTEP) {
            WLOAD(s + 2, wnxt[0]);
            WLOAD(s + 3, wnxt[1]);
        }
#pragma unroll
        for (int half = 0; half < 2; ++half) {
            const short* SB = SBc + half * 64 * 64;
            short8v af[2];
#pragma unroll
            for (int kf = 0; kf < 2; ++kf) {
                int row = wv * 16 + (lane & 15);
                int c8 = kf * 4 + (lane >> 4);
                af[kf] = *(const short8v*)&SB[row * 64 + ((c8 ^ (row & 7)) << 3)];
            }
            __builtin_amdgcn_s_setprio(1);
#pragma unroll
            for (int kf = 0; kf < 2; ++kf)
#pragma unroll
                for (int oi = 0; oi < 2; ++oi)
                    acc[oi] = __builtin_amdgcn_mfma_f32_16x16x32_bf16(
                        af[kf], __builtin_bit_cast(short8v, wcur[half][kf * 2 + oi]),
                        acc[oi], 0, 0, 0);
            __builtin_amdgcn_s_setprio(0);
        }
        asm volatile("s_waitcnt lgkmcnt(0)" ::: "memory");
    };

    for (int s4 = 0; s4 < NSTEP; s4 += 4) {
        ITER2(s4, wA, wB, aP, aQ, &S_s[0][0], &S_s[2][0]);
        ITER2(s4 + 2, wB, wA, aQ, aP, &S_s[2][0], &S_s[0][0]);
    }

#pragma unroll
    for (int j = 0; j < 4; ++j) {
        int p2 = px0 + wv * 16 + (lane >> 4) * 4 + j;
#pragma unroll
        for (int oi = 0; oi < 2; ++oi) {
            int o = oi * 16 + (lane & 15);
            offp[(size_t)p2 * 32 + o] = fmaxf(acc[oi][j] + bia[oi], 0.f);
        }
    }
}

// ---------------------------------------------------------------- dcn GEMM: 64px x 256o, 8 waves, ITER2 (R11/R13)
__global__ __launch_bounds__(512) void k_dcng(const unsigned short* __restrict__ xth,
                                              const float* __restrict__ offp,
                                              const unsigned short* __restrict__ wbf,
                                              const float* __restrict__ xn,
                                              float* __restrict__ out) {
    __shared__ short S_s[4][64 * 64];                 // 4 bufs, 32 KB
    const int tid = threadIdx.x;
    const int bid = blockIdx.x;
    const int px0 = ((bid & 7) * 32 + (bid >> 3)) * 64;   // XCD-bijective
    const int b = px0 >> 12;
    const unsigned short* xb = xth + (size_t)b * HPIX * 256;
    const int pxl = tid >> 3;
    const int px = px0 + pxl;
    const int y = (px & 4095) >> 6, x = px & 63;
    const int u0 = tid & 7;
    const int lane = tid & 63, wv = tid >> 6;
    const unsigned short* wfb = wbf + (size_t)wv * NSTEP * 2048 + lane * 8;
    const float2* offv = (const float2*)offp;

    f32x4 acc[2][4] = {};
    u32x4 wA[2][4], wB[2][4];
    u32x4 g[2][4];
    const int wr0 = pxl * 64 + ((u0 ^ (pxl & 7)) << 3);

    const unsigned short* pcorner[4];
    f32x2 wpair[4];
    float2 offn;

    auto SETUP = [&](int tap, float dyo, float dxo) {
        int ky = tap / 3 - 1, kx = tap % 3 - 1;
        float ypos = (float)(y + ky) + dyo;
        float xpos = (float)(x + kx) + dxo;
        float y0f = floorf(ypos), x0f = floorf(xpos);
        float wy = ypos - y0f, wx = xpos - x0f;
        int y0 = (int)y0f, x0 = (int)x0f;
        bool y0v = (y0 >= 0) && (y0 < Hh), y1v = (y0 + 1 >= 0) && (y0 + 1 < Hh);
        bool x0v = (x0 >= 0) && (x0 < Wwd), x1v = (x0 + 1 >= 0) && (x0 + 1 < Wwd);
        int hy0 = min(max(y0, -1), 64) + 1, hy1 = min(max(y0 + 1, -1), 64) + 1;
        int hx0 = min(max(x0, -1), 64) + 1, hx1 = min(max(x0 + 1, -1), 64) + 1;
        float w0 = (1.f - wy) * (1.f - wx) * (float)(y0v && x0v);
        float w1 = (1.f - wy) * wx * (float)(y0v && x1v);
        float w2 = wy * (1.f - wx) * (float)(y1v && x0v);
        float w3 = wy * wx * (float)(y1v && x1v);
        wpair[0] = (f32x2){w0, w0};
        wpair[1] = (f32x2){w1, w1};
        wpair[2] = (f32x2){w2, w2};
        wpair[3] = (f32x2){w3, w3};
        pcorner[0] = xb + (size_t)((hy0 * HH + hx0) * 256) + u0 * 8;
        pcorner[1] = xb + (size_t)((hy0 * HH + hx1) * 256) + u0 * 8;
        pcorner[2] = xb + (size_t)((hy1 * HH + hx0) * 256) + u0 * 8;
        pcorner[3] = xb + (size_t)((hy1 * HH + hx1) * 256) + u0 * 8;
    };
    auto WLOAD = [&](int s, u32x4 (&wreg)[4]) {
#pragma unroll
        for (int f = 0; f < 4; ++f)
            wreg[f] = *(const u32x4*)(wfb + ((size_t)s * 4 + f) * 512);
    };
    auto GISSUE = [&](int s, u32x4 (&gr)[4]) {
        const int nco = (s & 3) * 64;
#pragma unroll
        for (int c = 0; c < 4; ++c) gr[c] = *(const u32x4*)(pcorner[c] + nco);
    };
    auto COMBINE_WRITE = [&](u32x4 (&gr)[4], short* SBn) {
        u32x4 res;
#pragma unroll
        for (int qd = 0; qd < 4; ++qd) {
            f32x2 a = pk_mul(unpack2(gr[0][qd]), wpair[0]);
            a = pk_fma(unpack2(gr[1][qd]), wpair[1], a);
            a = pk_fma(unpack2(gr[2][qd]), wpair[2], a);
            a = pk_fma(unpack2(gr[3][qd]), wpair[3], a);
            res[qd] = cvt_pk_bf16(a.x, a.y);
        }
        *(u32x4*)&SBn[wr0] = res;
    };

    {
        float2 o0 = offv[(size_t)px * 16];
        SETUP(0, o0.x, o0.y);
        u32x4 g0[4], g1[4];
        GISSUE(0, g0);
        GISSUE(1, g1);
        WLOAD(0, wA[0]);
        WLOAD(1, wA[1]);
        COMBINE_WRITE(g0, &S_s[0][0]);
        COMBINE_WRITE(g1, &S_s[1][0]);
        GISSUE(2, g[0]);
        GISSUE(3, g[1]);
        offn = offv[(size_t)px * 16 + 1];
        asm volatile("s_waitcnt lgkmcnt(0)" ::: "memory");
    }

    auto ITER2 = [&](int s, u32x4 (&wcur)[2][4], u32x4 (&wnxt)[2][4], short* SBc, short* SBn) {
        __builtin_amdgcn_s_barrier();
        __builtin_amdgcn_sched_barrier(0);
        if (s + 2 < NSTEP) {
            COMBINE_WRITE(g[0], SBn);
            COMBINE_WRITE(g[1], SBn + 64 * 64);
        }
        if ((s & 3) == 0 && s + 4 < NSTEP)
            SETUP((s + 4) >> 2, offn.x, offn.y);
        if ((s & 3) == 2 && ((s + 8) >> 2) < 9)
            offn = offv[(size_t)px * 16 + ((s + 8) >> 2)];
        if (s + 4 < NSTEP) {
            GISSUE(s + 4, g[0]);
            GISSUE(s + 5, g[1]);
        }
        if (s + 2 < NSTEP) {
            WLOAD(s + 2, wnxt[0]);
            WLOAD(s + 3, wnxt[1]);
        }
#pragma unroll
        for (int half = 0; half < 2; ++half) {
            const short* SB = SBc + half * 64 * 64;
            short8v sf[4][2];
#pragma unroll
            for (int ni = 0; ni < 4; ++ni) {
                int row = ni * 16 + (lane & 15);
#pragma unroll
                for (int kf = 0; kf < 2; ++kf) {
                    int c8 = kf * 4 + (lane >> 4);
                    sf[ni][kf] = *(const short8v*)&SB[row * 64 + ((c8 ^ (row & 7)) << 3)];
                }
            }
            __builtin_amdgcn_s_setprio(1);
#pragma unroll
            for (int kf = 0; kf < 2; ++kf)
#pragma unroll
                for (int mi = 0; mi < 2; ++mi)
#pragma unroll
                    for (int ni = 0; ni < 4; ++ni)
                        acc[mi][ni] = __builtin_amdgcn_mfma_f32_16x16x32_bf16(
                            __builtin_bit_cast(short8v, wcur[half][kf * 2 + mi]), sf[ni][kf],
                            acc[mi][ni], 0, 0, 0);
            __builtin_amdgcn_s_setprio(0);
        }
        asm volatile("s_waitcnt lgkmcnt(0)" ::: "memory");
    };

    for (int s4 = 0; s4 < NSTEP; s4 += 4) {
        ITER2(s4, wA, wB, &S_s[0][0], &S_s[2][0]);
        ITER2(s4 + 2, wB, wA, &S_s[2][0], &S_s[0][0]);
    }

#pragma unroll
    for (int mi = 0; mi < 2; ++mi) {
        int o = wv * 32 + mi * 16 + (lane >> 4) * 4;
#pragma unroll
        for (int j = 0; j < 4; ++j) {
            size_t rowbase = ((size_t)b * 256 + o + j) * HWp;
#pragma unroll
            for (int ni = 0; ni < 4; ++ni) {
                int p2 = (px0 + ni * 16 + (lane & 15)) & 4095;
                size_t idx = rowbase + p2;
                out[idx] = 0.5f * (xn[idx] + fmaxf(acc[mi][ni][j], 0.f));
            }
        }
    }
}

extern "C" void kernel_launch(void* const* d_in, const int* in_sizes, int n_in,
                              void* d_out, int out_size, void* d_ws, size_t ws_size,
                              hipStream_t stream) {
    const float* x_ref  = (const float*)d_in[0];
    const float* x_next = (const float*)d_in[1];
    const float* w1 = (const float*)d_in[2];
    const float* b1 = (const float*)d_in[3];
    const float* w2 = (const float*)d_in[4];
    const float* b2 = (const float*)d_in[5];
    const float* w3 = (const float*)d_in[6];
    const float* b3 = (const float*)d_in[7];
    const float* wd = (const float*)d_in[8];
    float* out = (float*)d_out;
    char* ws = (char*)d_ws;

    unsigned short* h1h = (unsigned short*)(ws + B_H1H);
    unsigned short* h2h = (unsigned short*)(ws + B_H2H);
    unsigned short* xth = (unsigned short*)(ws + B_XTH);
    float* prod = (float*)(ws + B_PROD);
    float* offp = (float*)(ws + B_OFFP);
    unsigned short* wb2f = (unsigned short*)(ws + B_WB2);
    unsigned short* wbdf = (unsigned short*)(ws + B_WBD);
    unsigned short* wb3f = (unsigned short*)(ws + B_WB3);

    k_zero_ring<<<3120 + 128, 128, 0, stream>>>(h1h, h2h, xth, prod);
    k_prodx<<<dim3(128, 8, Bsz), dim3(32, 8), 0, stream>>>(x_ref, x_next, xth, prod);
    k_packall<<<4896, 256, 0, stream>>>(w2, wd, w3, wb2f, wbdf, wb3f);
    k_conv1c<<<NPIX / 32, 256, 0, stream>>>(prod, w1, b1, h1h);
    k_conv2g<<<512, 256, 0, stream>>>(h1h, wb2f, b2, h2h);
    k_conv3g<<<256, 256, 0, stream>>>(h2h, wb3f, b3, offp);
    k_dcng<<<256, 512, 0, stream>>>(xth, offp, wbdf, x_next, out);
}